// Round 4
// baseline (69.335 us; speedup 1.0000x reference)
//
#include <hip/hip_runtime.h>
#include <stdint.h>

#define B 512
#define D 128
#define HALFC 131072u

__device__ __forceinline__ uint32_t rotl32(uint32_t x, uint32_t r) {
  return (x << r) | (x >> (32u - r));
}

// Exact JAX/XLA threefry2x32 (20 rounds, key-schedule injections every 4).
__device__ __forceinline__ void threefry2x32(uint32_t k0, uint32_t k1,
                                             uint32_t x0, uint32_t x1,
                                             uint32_t& y0, uint32_t& y1) {
  uint32_t k2 = k0 ^ k1 ^ 0x1BD11BDAu;
  x0 += k0; x1 += k1;
#define TF_R(r) { x0 += x1; x1 = rotl32(x1, r); x1 ^= x0; }
  TF_R(13) TF_R(15) TF_R(26) TF_R(6)
  x0 += k1; x1 += k2 + 1u;
  TF_R(17) TF_R(29) TF_R(16) TF_R(24)
  x0 += k2; x1 += k0 + 2u;
  TF_R(13) TF_R(15) TF_R(26) TF_R(6)
  x0 += k0; x1 += k1 + 3u;
  TF_R(17) TF_R(29) TF_R(16) TF_R(24)
  x0 += k1; x1 += k2 + 4u;
  TF_R(13) TF_R(15) TF_R(26) TF_R(6)
  x0 += k2; x1 += k0 + 5u;
#undef TF_R
  y0 = x0; y1 = x1;
}

// One block per row i. 512 threads (8 waves).
// Phase 1: dist row i into LDS (fused sq), hard-negative argmin, anchor list.
// Phase 2: waves iterate same-label anchors p; per-anchor candidate
//          compaction + threefry argmax (lex: bits desc, j asc).
__global__ __launch_bounds__(512) void main_kernel(
    const float* __restrict__ emb, const int* __restrict__ labels,
    double* __restrict__ partials, int* __restrict__ pcnt) {
  __shared__ unsigned short slab[B];
  __shared__ unsigned short list_sh[B];
  __shared__ unsigned short cand[8][B];
  __shared__ float drow[B];
  __shared__ float ei[D];
  __shared__ float sqi_sh;
  __shared__ float rmin[B];
  __shared__ int ridx[B];
  __shared__ int nlist_sh;
  __shared__ int hard_sh;
  __shared__ double lsum[8];
  __shared__ unsigned int lcnt[8];

  int i = blockIdx.x;
  int t = threadIdx.x;
  slab[t] = (unsigned short)labels[t];
  if (t < D) ei[t] = emb[(size_t)i * D + t];
  __syncthreads();

  // --- Phase 1: column j = t ---
  const float4* e4i = reinterpret_cast<const float4*>(ei);
  const float4* ej = reinterpret_cast<const float4*>(emb + (size_t)t * D);
  float dacc = 0.f, sacc = 0.f;
  #pragma unroll
  for (int d4 = 0; d4 < D / 4; ++d4) {
    float4 v = ej[d4];
    float4 w = e4i[d4];
    dacc += v.x * w.x + v.y * w.y + v.z * w.z + v.w * w.w;
    sacc += v.x * v.x + v.y * v.y + v.z * v.z + v.w * v.w;
  }
  if (t == i) sqi_sh = sacc;
  __syncthreads();
  unsigned short lab_i = slab[i];
  float dd_t = sqrtf(fmaxf(sqi_sh + sacc - 2.f * dacc, 0.f));
  drow[t] = dd_t;
  bool isneg = (slab[t] != lab_i);
  rmin[t] = isneg ? dd_t : 3.4e38f;
  ridx[t] = isneg ? t : -1;
  __syncthreads();
  // argmin over negatives, ties -> lowest j (first occurrence)
  for (int s = 256; s; s >>= 1) {
    if (t < s) {
      float ov = rmin[t + s]; int oj = ridx[t + s];
      if (oj >= 0 && (ridx[t] < 0 || ov < rmin[t] ||
                      (ov == rmin[t] && oj < ridx[t]))) {
        rmin[t] = ov; ridx[t] = oj;
      }
    }
    __syncthreads();
  }

  int wave = t >> 6, lane = t & 63;
  unsigned long long lmask_lt = (1ull << lane) - 1ull;

  // wave 0: ascending list of same-label anchors (includes i; skipped later)
  if (wave == 0) {
    int n = 0;
    #pragma unroll
    for (int c = 0; c < 8; ++c) {
      int r = c * 64 + lane;
      bool v = (slab[r] == lab_i);
      unsigned long long mk = __ballot(v);
      if (v) list_sh[n + __popcll(mk & lmask_lt)] = (unsigned short)r;
      n += __popcll(mk);
    }
    if (lane == 0) {
      nlist_sh = (ridx[0] < 0) ? 0 : n;  // no negatives -> has_neg false
      hard_sh = (ridx[0] < 0) ? 0 : ridx[0];
    }
  }
  __syncthreads();
  int n = nlist_sh;
  int hard = hard_sh;

  // row-invariant per-lane data
  float dd8[8];
  bool negm[8];
  #pragma unroll
  for (int jc = 0; jc < 8; ++jc) {
    int j = jc * 64 + lane;
    dd8[jc] = drow[j];
    negm[jc] = (slab[j] != lab_i);
  }

  // lane-parallel key precompute: lane l holds key for this wave's l-th anchor
  // keys[p] from split(key(42), 512): out[q] = q<512 ? y0(q,q+512) : y1(q-512,q)
  uint32_t key0 = 0, key1 = 0;
  int p_l = -1;
  int kidx = wave + 8 * lane;
  if (kidx < n) {
    int p = list_sh[kidx];
    uint32_t i0 = 2u * (uint32_t)p, i1 = i0 + 1u;
    uint32_t a0, a1, b0, b1;
    if (p < 256) {
      threefry2x32(0u, 42u, i0, i0 + 512u, a0, a1);
      threefry2x32(0u, 42u, i1, i1 + 512u, b0, b1);
      key0 = a0; key1 = b0;
    } else {
      threefry2x32(0u, 42u, i0 - 512u, i0, a0, a1);
      threefry2x32(0u, 42u, i1 - 512u, i1, b0, b1);
      key0 = a1; key1 = b1;
    }
    p_l = p;
  }

  uint32_t rowbase = (uint32_t)(((i < 256) ? i : (i - 256)) * B);
  bool take_hi = (i >= 256);
  unsigned short* wcand = cand[wave];
  double wsum = 0.0;
  unsigned int wcnt = 0;
  int nanch = (n > wave) ? ((n - wave + 7) >> 3) : 0;

  for (int a = 0; a < nanch; ++a) {
    int p = __shfl(p_l, a);
    if (p == i) continue;
    uint32_t kp0 = (uint32_t)__shfl((int)key0, a);
    uint32_t kp1 = (uint32_t)__shfl((int)key1, a);
    float pos_d = drow[p];
    float hiv = pos_d + 1.0f;  // margin = 1.0

    int nc = 0;
    #pragma unroll
    for (int jc = 0; jc < 8; ++jc) {
      bool m = negm[jc] && (dd8[jc] > pos_d) && (dd8[jc] < hiv);
      unsigned long long mk = __ballot(m);
      if (m) wcand[nc + __popcll(mk & lmask_lt)] =
          (unsigned short)(jc * 64 + lane);
      nc += __popcll(mk);
    }

    uint32_t bestbits = 0u;
    int bestj = -1;
    for (int c = lane; c < nc; c += 64) {
      int j = wcand[c];
      uint32_t y0, y1;
      threefry2x32(kp0, kp1, rowbase + (uint32_t)j,
                   rowbase + (uint32_t)j + HALFC, y0, y1);
      uint32_t bits = (take_hi ? y1 : y0) >> 9;
      // within-lane j ascends: strict > keeps lowest j among ties
      if (bestj < 0 || bits > bestbits) { bestbits = bits; bestj = j; }
    }
    // cross-lane lexicographic reduce: max bits, ties -> min j
    #pragma unroll
    for (int off = 32; off; off >>= 1) {
      uint32_t ob = (uint32_t)__shfl_xor((int)bestbits, off);
      int oj = __shfl_xor(bestj, off);
      if (oj >= 0 && (bestj < 0 || ob > bestbits ||
                      (ob == bestbits && oj < bestj))) {
        bestbits = ob; bestj = oj;
      }
    }
    int idx = (bestj >= 0) ? bestj : hard;
    float neg_d = drow[idx];
    float tl = pos_d - neg_d + 1.0f;
    if (tl > 0.f) { wsum += (double)tl; wcnt++; }
  }

  if (lane == 0) { lsum[wave] = wsum; lcnt[wave] = wcnt; }
  __syncthreads();
  if (t == 0) {
    double s = 0.0;
    unsigned int c = 0;
    #pragma unroll
    for (int w = 0; w < 8; ++w) { s += lsum[w]; c += lcnt[w]; }
    partials[i] = s;
    pcnt[i] = (int)c;
  }
}

// Deterministic fixed-order reduction of the 512 block partials.
__global__ __launch_bounds__(256) void finalize_kernel(
    const double* __restrict__ partials, const int* __restrict__ pcnt,
    float* __restrict__ out) {
  __shared__ double ss[256];
  __shared__ int sc[256];
  int t = threadIdx.x;
  double s = partials[t] + partials[t + 256];
  int c = pcnt[t] + pcnt[t + 256];
  ss[t] = s; sc[t] = c;
  __syncthreads();
  for (int st = 128; st; st >>= 1) {
    if (t < st) { ss[t] += ss[t + st]; sc[t] += sc[t + st]; }
    __syncthreads();
  }
  if (t == 0) out[0] = sc[0] ? (float)(ss[0] / (double)sc[0]) : 0.0f;
}

extern "C" void kernel_launch(void* const* d_in, const int* in_sizes, int n_in,
                              void* d_out, int out_size, void* d_ws, size_t ws_size,
                              hipStream_t stream) {
  const float* emb = (const float*)d_in[0];
  const int* labels = (const int*)d_in[1];
  float* out = (float*)d_out;
  char* ws = (char*)d_ws;

  double* partials = (double*)ws;        // 4 KB
  int* pcnt = (int*)(ws + 4096);         // 2 KB

  main_kernel<<<B, 512, 0, stream>>>(emb, labels, partials, pcnt);
  finalize_kernel<<<1, 256, 0, stream>>>(partials, pcnt, out);
}

// Round 5
// 58.778 us; speedup vs baseline: 1.1796x; 1.1796x over previous
//
#include <hip/hip_runtime.h>
#include <stdint.h>

#define B 512
#define D 128
#define HALFC 131072u
#define SPLIT 8
#define NSLOT (SPLIT * 4)
#define NPART (B * SPLIT)

__device__ __forceinline__ uint32_t rotl32(uint32_t x, uint32_t r) {
  return (x << r) | (x >> (32u - r));
}

// Exact JAX/XLA threefry2x32 (20 rounds, key-schedule injections every 4).
__device__ __forceinline__ void threefry2x32(uint32_t k0, uint32_t k1,
                                             uint32_t x0, uint32_t x1,
                                             uint32_t& y0, uint32_t& y1) {
  uint32_t k2 = k0 ^ k1 ^ 0x1BD11BDAu;
  x0 += k0; x1 += k1;
#define TF_R(r) { x0 += x1; x1 = rotl32(x1, r); x1 ^= x0; }
  TF_R(13) TF_R(15) TF_R(26) TF_R(6)
  x0 += k1; x1 += k2 + 1u;
  TF_R(17) TF_R(29) TF_R(16) TF_R(24)
  x0 += k2; x1 += k0 + 2u;
  TF_R(13) TF_R(15) TF_R(26) TF_R(6)
  x0 += k0; x1 += k1 + 3u;
  TF_R(17) TF_R(29) TF_R(16) TF_R(24)
  x0 += k1; x1 += k2 + 4u;
  TF_R(13) TF_R(15) TF_R(26) TF_R(6)
  x0 += k2; x1 += k0 + 5u;
#undef TF_R
  y0 = x0; y1 = x1;
}

// Two independent threefry chains interleaved (ILP for the serial rounds).
__device__ __forceinline__ void threefry2x32_dual(
    uint32_t k0, uint32_t k1, uint32_t a0, uint32_t a1, uint32_t b0,
    uint32_t b1, uint32_t& ya0, uint32_t& ya1, uint32_t& yb0, uint32_t& yb1) {
  uint32_t k2 = k0 ^ k1 ^ 0x1BD11BDAu;
  a0 += k0; a1 += k1; b0 += k0; b1 += k1;
#define TF_R2(r) { a0 += a1; a1 = rotl32(a1, r); a1 ^= a0; \
                   b0 += b1; b1 = rotl32(b1, r); b1 ^= b0; }
  TF_R2(13) TF_R2(15) TF_R2(26) TF_R2(6)
  a0 += k1; a1 += k2 + 1u; b0 += k1; b1 += k2 + 1u;
  TF_R2(17) TF_R2(29) TF_R2(16) TF_R2(24)
  a0 += k2; a1 += k0 + 2u; b0 += k2; b1 += k0 + 2u;
  TF_R2(13) TF_R2(15) TF_R2(26) TF_R2(6)
  a0 += k0; a1 += k1 + 3u; b0 += k0; b1 += k1 + 3u;
  TF_R2(17) TF_R2(29) TF_R2(16) TF_R2(24)
  a0 += k1; a1 += k2 + 4u; b0 += k1; b1 += k2 + 4u;
  TF_R2(13) TF_R2(15) TF_R2(26) TF_R2(6)
  a0 += k2; a1 += k0 + 5u; b0 += k2; b1 += k0 + 5u;
#undef TF_R2
  ya0 = a0; ya1 = a1; yb0 = b0; yb1 = b1;
}

// K1: dist row i (fused sq) + hard-negative argmin + per-anchor key i.
__global__ __launch_bounds__(256) void dist_kernel(
    const float* __restrict__ emb, const int* __restrict__ labels,
    float* __restrict__ dist, int* __restrict__ hard_idx,
    uint32_t* __restrict__ keys0, uint32_t* __restrict__ keys1) {
  __shared__ float ei[D];
  __shared__ float sqi_sh;
  __shared__ float rmin[256];
  __shared__ int ridx[256];
  int i = blockIdx.x;
  int t = threadIdx.x;
  if (t < D) ei[t] = emb[(size_t)i * D + t];
  __syncthreads();

  // thread 255 computes keys[i] (overlaps with everyone's dot products)
  if (t == 255) {
    uint32_t i0 = 2u * (uint32_t)i, i1 = i0 + 1u;
    uint32_t a0, a1, b0, b1;
    if (i < 256) {
      threefry2x32(0u, 42u, i0, i0 + 512u, a0, a1);
      threefry2x32(0u, 42u, i1, i1 + 512u, b0, b1);
      keys0[i] = a0; keys1[i] = b0;
    } else {
      threefry2x32(0u, 42u, i0 - 512u, i0, a0, a1);
      threefry2x32(0u, 42u, i1 - 512u, i1, b0, b1);
      keys0[i] = a1; keys1[i] = b1;
    }
  }

  const float4* e4i = reinterpret_cast<const float4*>(ei);
  float dot[2], sj[2];
  #pragma unroll
  for (int jj = 0; jj < 2; ++jj) {
    int j = t + jj * 256;
    const float4* ej = reinterpret_cast<const float4*>(emb + (size_t)j * D);
    float dacc = 0.f, sacc = 0.f;
    #pragma unroll 8
    for (int d4 = 0; d4 < D / 4; ++d4) {
      float4 v = ej[d4];
      float4 w = e4i[d4];
      dacc += v.x * w.x + v.y * w.y + v.z * w.z + v.w * w.w;
      sacc += v.x * v.x + v.y * v.y + v.z * v.z + v.w * v.w;
    }
    dot[jj] = dacc; sj[jj] = sacc;
    if (j == i) sqi_sh = sacc;
  }
  __syncthreads();
  float sqi = sqi_sh;
  int lab_i = labels[i];
  float bestv = 3.4e38f;
  int bestj = -1;
  #pragma unroll
  for (int jj = 0; jj < 2; ++jj) {
    int j = t + jj * 256;
    float d2 = sqi + sj[jj] - 2.f * dot[jj];
    float dd = sqrtf(fmaxf(d2, 0.f));
    dist[(size_t)i * B + j] = dd;
    if (labels[j] != lab_i) {
      if (bestj < 0 || dd < bestv) { bestv = dd; bestj = j; } // j asc -> first min
    }
  }
  rmin[t] = bestv; ridx[t] = bestj;
  __syncthreads();
  for (int s = 128; s; s >>= 1) {
    if (t < s) {
      float ov = rmin[t + s]; int oj = ridx[t + s];
      if (oj >= 0 && (ridx[t] < 0 || ov < rmin[t] ||
                      (ov == rmin[t] && oj < ridx[t]))) {
        rmin[t] = ov; ridx[t] = oj;
      }
    }
    __syncthreads();
  }
  if (t == 0) hard_idx[i] = (ridx[0] < 0) ? 0 : ridx[0];
}

// K2: SPLIT blocks per anchor p; candidate compaction; dual-threefry ILP;
// packed-u32 lexicographic argmax (bits desc, j asc).
__global__ __launch_bounds__(256) void triplet_kernel(
    const float* __restrict__ dist, const int* __restrict__ labels,
    const int* __restrict__ hard_idx, const uint32_t* __restrict__ keys0,
    const uint32_t* __restrict__ keys1, double* __restrict__ partials,
    int* __restrict__ pcnt) {
  __shared__ unsigned short slab[B];
  __shared__ unsigned short list_sh[B];
  __shared__ unsigned short cand[4][B];
  __shared__ int nlist_sh;
  __shared__ double lsum[4];
  __shared__ unsigned int lcnt[4];
  int bid = blockIdx.x;
  int p = bid >> 3;  // SPLIT = 8
  int sub = bid & 7;
  int t = threadIdx.x;
  int lab_p = labels[p];  // wave-uniform broadcast load, no LDS dependency
  slab[t] = (unsigned short)labels[t];
  slab[t + 256] = (unsigned short)labels[t + 256];
  __syncthreads();
  int wave = t >> 6, lane = t & 63;
  int slot = sub * 4 + wave;
  unsigned long long lmask_lt = (1ull << lane) - 1ull;

  // wave 0 builds the ascending list of rows with label lab_p
  if (wave == 0) {
    int n = 0;
    #pragma unroll
    for (int c = 0; c < 8; ++c) {
      int r = c * 64 + lane;
      bool v = (slab[r] == (unsigned short)lab_p);
      unsigned long long mk = __ballot(v);
      if (v) list_sh[n + __popcll(mk & lmask_lt)] = (unsigned short)r;
      n += __popcll(mk);
    }
    if (lane == 0) nlist_sh = (n == B) ? 0 : n;  // n==B -> no negatives
  }

  // pair-invariant per-lane 8-bit negative-label mask
  uint32_t negm = 0;
  #pragma unroll
  for (int jc = 0; jc < 8; ++jc)
    negm |= (uint32_t)(slab[jc * 64 + lane] != (unsigned short)lab_p) << jc;

  uint32_t kp0 = keys0[p], kp1 = keys1[p];
  __syncthreads();
  int nlist = nlist_sh;
  unsigned short* wcand = cand[wave];
  double wsum = 0.0;
  unsigned int wcnt = 0;

  for (int k = slot; k < nlist; k += NSLOT) {
    int i = list_sh[k];
    if (i == p) continue;
    const float* __restrict__ drow = dist + (size_t)i * B;
    float pos_d = drow[p];
    float hiv = pos_d + 1.0f;  // margin = 1.0
    float dd8[8];
    #pragma unroll
    for (int jc = 0; jc < 8; ++jc) dd8[jc] = drow[jc * 64 + lane];
    uint32_t rowbase = (uint32_t)((i & 255) * B);
    bool take_hi = (i >= 256);

    int nc = 0;
    #pragma unroll
    for (int jc = 0; jc < 8; ++jc) {
      bool m = ((negm >> jc) & 1u) && (dd8[jc] > pos_d) && (dd8[jc] < hiv);
      unsigned long long mk = __ballot(m);
      if (m) wcand[nc + __popcll(mk & lmask_lt)] =
          (unsigned short)(jc * 64 + lane);
      nc += __popcll(mk);
    }

    int idx;
    if (nc > 0) {
      // packed key: (bits23 << 9) | (511 - j); max -> max bits, tie -> min j
      uint32_t best = 0u;
      for (int c = lane; c < nc; c += 128) {
        int j1 = wcand[c];
        int c2 = c + 64;
        int j2 = (c2 < nc) ? wcand[c2] : j1;
        uint32_t ya0, ya1, yb0, yb1;
        threefry2x32_dual(kp0, kp1,
                          rowbase + (uint32_t)j1, rowbase + (uint32_t)j1 + HALFC,
                          rowbase + (uint32_t)j2, rowbase + (uint32_t)j2 + HALFC,
                          ya0, ya1, yb0, yb1);
        uint32_t y1v = take_hi ? ya1 : ya0;
        uint32_t key1 = (y1v & 0xFFFFFE00u) | (uint32_t)(511 - j1);
        if (key1 > best) best = key1;
        if (c2 < nc) {
          uint32_t y2v = take_hi ? yb1 : yb0;
          uint32_t key2 = (y2v & 0xFFFFFE00u) | (uint32_t)(511 - j2);
          if (key2 > best) best = key2;
        }
      }
      #pragma unroll
      for (int off = 32; off; off >>= 1) {
        uint32_t ob = (uint32_t)__shfl_xor((int)best, off);
        if (ob > best) best = ob;
      }
      idx = 511 - (int)(best & 0x1FFu);
    } else {
      idx = hard_idx[i];
    }
    float neg_d = drow[idx];
    float tl = pos_d - neg_d + 1.0f;
    if (tl > 0.f) { wsum += (double)tl; wcnt++; }
  }

  if (lane == 0) { lsum[wave] = wsum; lcnt[wave] = wcnt; }
  __syncthreads();
  if (t == 0) {
    partials[bid] = lsum[0] + lsum[1] + lsum[2] + lsum[3];
    pcnt[bid] = (int)(lcnt[0] + lcnt[1] + lcnt[2] + lcnt[3]);
  }
}

// K3: deterministic fixed-order reduction of the 4096 block partials.
__global__ __launch_bounds__(256) void finalize_kernel(
    const double* __restrict__ partials, const int* __restrict__ pcnt,
    float* __restrict__ out) {
  __shared__ double ss[256];
  __shared__ int sc[256];
  int t = threadIdx.x;
  double s = 0.0;
  int c = 0;
  for (int k = t; k < NPART; k += 256) { s += partials[k]; c += pcnt[k]; }
  ss[t] = s; sc[t] = c;
  __syncthreads();
  for (int st = 128; st; st >>= 1) {
    if (t < st) { ss[t] += ss[t + st]; sc[t] += sc[t + st]; }
    __syncthreads();
  }
  if (t == 0) out[0] = sc[0] ? (float)(ss[0] / (double)sc[0]) : 0.0f;
}

extern "C" void kernel_launch(void* const* d_in, const int* in_sizes, int n_in,
                              void* d_out, int out_size, void* d_ws, size_t ws_size,
                              hipStream_t stream) {
  const float* emb = (const float*)d_in[0];
  const int* labels = (const int*)d_in[1];
  float* out = (float*)d_out;
  char* ws = (char*)d_ws;

  float* dist = (float*)ws;                            // 1 MB
  int* hard_idx = (int*)(ws + 1048576);                // 2 KB
  uint32_t* keys0 = (uint32_t*)(ws + 1048576 + 2048);  // 2 KB
  uint32_t* keys1 = (uint32_t*)(ws + 1048576 + 4096);  // 2 KB
  double* partials = (double*)(ws + 1048576 + 6144);   // 32 KB
  int* pcnt = (int*)(ws + 1048576 + 6144 + 32768);     // 16 KB

  dist_kernel<<<B, 256, 0, stream>>>(emb, labels, dist, hard_idx, keys0, keys1);
  triplet_kernel<<<B * SPLIT, 256, 0, stream>>>(dist, labels, hard_idx, keys0,
                                                keys1, partials, pcnt);
  finalize_kernel<<<1, 256, 0, stream>>>(partials, pcnt, out);
}

// Round 6
// 53.589 us; speedup vs baseline: 1.2938x; 1.0968x over previous
//
#include <hip/hip_runtime.h>
#include <stdint.h>

#define B 512
#define D 128
#define HALFC 131072u
#define SUB 4
#define NSLOT (SUB * 4)
#define NPART (B * SUB)

__device__ __forceinline__ uint32_t rotl32(uint32_t x, uint32_t r) {
  return (x << r) | (x >> (32u - r));
}

// Exact JAX/XLA threefry2x32 (20 rounds, key-schedule injections every 4).
__device__ __forceinline__ void threefry2x32(uint32_t k0, uint32_t k1,
                                             uint32_t x0, uint32_t x1,
                                             uint32_t& y0, uint32_t& y1) {
  uint32_t k2 = k0 ^ k1 ^ 0x1BD11BDAu;
  x0 += k0; x1 += k1;
#define TF_R(r) { x0 += x1; x1 = rotl32(x1, r); x1 ^= x0; }
  TF_R(13) TF_R(15) TF_R(26) TF_R(6)
  x0 += k1; x1 += k2 + 1u;
  TF_R(17) TF_R(29) TF_R(16) TF_R(24)
  x0 += k2; x1 += k0 + 2u;
  TF_R(13) TF_R(15) TF_R(26) TF_R(6)
  x0 += k0; x1 += k1 + 3u;
  TF_R(17) TF_R(29) TF_R(16) TF_R(24)
  x0 += k1; x1 += k2 + 4u;
  TF_R(13) TF_R(15) TF_R(26) TF_R(6)
  x0 += k2; x1 += k0 + 5u;
#undef TF_R
  y0 = x0; y1 = x1;
}

// Two independent threefry chains interleaved (ILP for the serial rounds).
__device__ __forceinline__ void threefry2x32_dual(
    uint32_t k0, uint32_t k1, uint32_t a0, uint32_t a1, uint32_t b0,
    uint32_t b1, uint32_t& ya0, uint32_t& ya1, uint32_t& yb0, uint32_t& yb1) {
  uint32_t k2 = k0 ^ k1 ^ 0x1BD11BDAu;
  a0 += k0; a1 += k1; b0 += k0; b1 += k1;
#define TF_R2(r) { a0 += a1; a1 = rotl32(a1, r); a1 ^= a0; \
                   b0 += b1; b1 = rotl32(b1, r); b1 ^= b0; }
  TF_R2(13) TF_R2(15) TF_R2(26) TF_R2(6)
  a0 += k1; a1 += k2 + 1u; b0 += k1; b1 += k2 + 1u;
  TF_R2(17) TF_R2(29) TF_R2(16) TF_R2(24)
  a0 += k2; a1 += k0 + 2u; b0 += k2; b1 += k0 + 2u;
  TF_R2(13) TF_R2(15) TF_R2(26) TF_R2(6)
  a0 += k0; a1 += k1 + 3u; b0 += k0; b1 += k1 + 3u;
  TF_R2(17) TF_R2(29) TF_R2(16) TF_R2(24)
  a0 += k1; a1 += k2 + 4u; b0 += k1; b1 += k2 + 4u;
  TF_R2(13) TF_R2(15) TF_R2(26) TF_R2(6)
  a0 += k2; a1 += k0 + 5u; b0 += k2; b1 += k0 + 5u;
#undef TF_R2
  ya0 = a0; ya1 = a1; yb0 = b0; yb1 = b1;
}

// K1: 512 threads, one column per thread. dist row i (fused sq) +
// packed-u64 wave argmin for hard negative + per-anchor key i.
__global__ __launch_bounds__(512) void dist_kernel(
    const float* __restrict__ emb, const int* __restrict__ labels,
    float* __restrict__ dist, int* __restrict__ hard_idx,
    uint32_t* __restrict__ keys0, uint32_t* __restrict__ keys1) {
  __shared__ float ei[D];
  __shared__ float sqi_sh;
  __shared__ unsigned long long wmin[8];
  int i = blockIdx.x;
  int t = threadIdx.x;
  if (t < D) ei[t] = emb[(size_t)i * D + t];
  __syncthreads();

  // thread 511 computes keys[i] (overlaps everyone's dot products)
  if (t == 511) {
    uint32_t i0 = 2u * (uint32_t)i, i1 = i0 + 1u;
    uint32_t a0, a1, b0, b1;
    if (i < 256) {
      threefry2x32(0u, 42u, i0, i0 + 512u, a0, a1);
      threefry2x32(0u, 42u, i1, i1 + 512u, b0, b1);
      keys0[i] = a0; keys1[i] = b0;
    } else {
      threefry2x32(0u, 42u, i0 - 512u, i0, a0, a1);
      threefry2x32(0u, 42u, i1 - 512u, i1, b0, b1);
      keys0[i] = a1; keys1[i] = b1;
    }
  }

  const float4* e4i = reinterpret_cast<const float4*>(ei);
  const float4* ej = reinterpret_cast<const float4*>(emb + (size_t)t * D);
  float dacc = 0.f, sacc = 0.f;
  #pragma unroll 8
  for (int d4 = 0; d4 < D / 4; ++d4) {
    float4 v = ej[d4];
    float4 w = e4i[d4];
    dacc += v.x * w.x + v.y * w.y + v.z * w.z + v.w * w.w;
    sacc += v.x * v.x + v.y * v.y + v.z * v.z + v.w * v.w;
  }
  if (t == i) sqi_sh = sacc;
  __syncthreads();
  float dd = sqrtf(fmaxf(sqi_sh + sacc - 2.f * dacc, 0.f));
  dist[(size_t)i * B + t] = dd;

  // argmin over negatives, ties -> lowest j: packed (fp32bits<<9 | j), min.
  bool isneg = (labels[t] != labels[i]);
  unsigned long long key =
      isneg ? (((unsigned long long)__float_as_uint(dd) << 9) | (unsigned)t)
            : ~0ull;
  #pragma unroll
  for (int off = 32; off; off >>= 1) {
    unsigned long long o = __shfl_xor(key, off);
    if (o < key) key = o;
  }
  int wave = t >> 6, lane = t & 63;
  if (lane == 0) wmin[wave] = key;
  __syncthreads();
  if (t == 0) {
    unsigned long long m = wmin[0];
    #pragma unroll
    for (int w = 1; w < 8; ++w)
      if (wmin[w] < m) m = wmin[w];
    hard_idx[i] = (m == ~0ull) ? -1 : (int)(m & 0x1FFu);
  }
}

// K2 (row-major): block = (row i, sub). drow staged once in LDS; dd8/negm
// row-invariant in registers; anchors share them. Per anchor: compaction +
// dual-threefry + packed-u32 lex argmax (bits desc, j asc).
__global__ __launch_bounds__(256) void triplet_kernel(
    const float* __restrict__ dist, const int* __restrict__ labels,
    const int* __restrict__ hard_idx, const uint32_t* __restrict__ keys0,
    const uint32_t* __restrict__ keys1, double* __restrict__ partials,
    int* __restrict__ pcnt) {
  __shared__ float drow[B];
  __shared__ unsigned short slab[B];
  __shared__ unsigned short list_sh[B];
  __shared__ unsigned short cand[4][B];
  __shared__ int nlist_sh;
  __shared__ double lsum[4];
  __shared__ unsigned int lcnt[4];

  int bid = blockIdx.x;
  int i = bid >> 2;  // SUB = 4
  int sub = bid & 3;
  int t = threadIdx.x;
  slab[t] = (unsigned short)labels[t];
  slab[t + 256] = (unsigned short)labels[t + 256];
  const float* __restrict__ dg = dist + (size_t)i * B;
  drow[t] = dg[t];
  drow[t + 256] = dg[t + 256];
  __syncthreads();

  int wave = t >> 6, lane = t & 63;
  unsigned long long lmask_lt = (1ull << lane) - 1ull;
  unsigned short lab_i = slab[i];

  // wave 0: ascending list of same-label anchors p (includes i; skipped later)
  if (wave == 0) {
    int n = 0;
    #pragma unroll
    for (int c = 0; c < 8; ++c) {
      int r = c * 64 + lane;
      bool v = (slab[r] == lab_i);
      unsigned long long mk = __ballot(v);
      if (v) list_sh[n + __popcll(mk & lmask_lt)] = (unsigned short)r;
      n += __popcll(mk);
    }
    if (lane == 0) nlist_sh = (n == B) ? 0 : n;  // n==B -> no negatives
  }

  // row-invariant per-lane data (reads drow/slab, already synced)
  float dd8[8];
  uint32_t negm = 0;
  #pragma unroll
  for (int jc = 0; jc < 8; ++jc) {
    int j = jc * 64 + lane;
    dd8[jc] = drow[j];
    negm |= (uint32_t)(slab[j] != lab_i) << jc;
  }
  int hard = hard_idx[i];
  uint32_t rowbase = (uint32_t)((i & 255) * B);
  bool take_hi = (i >= 256);
  __syncthreads();  // list_sh / nlist_sh ready

  int nlist = nlist_sh;
  unsigned short* wcand = cand[wave];
  double wsum = 0.0;
  unsigned int wcnt = 0;

  for (int k = sub * 4 + wave; k < nlist; k += NSLOT) {
    int p = list_sh[k];
    if (p == i) continue;
    p = __builtin_amdgcn_readfirstlane(p);  // wave-uniform
    uint32_t kp0 = keys0[p], kp1 = keys1[p];
    float pos_d = drow[p];
    float hiv = pos_d + 1.0f;  // margin = 1.0

    int nc = 0;
    #pragma unroll
    for (int jc = 0; jc < 8; ++jc) {
      bool m = ((negm >> jc) & 1u) && (dd8[jc] > pos_d) && (dd8[jc] < hiv);
      unsigned long long mk = __ballot(m);
      if (m) wcand[nc + __popcll(mk & lmask_lt)] =
          (unsigned short)(jc * 64 + lane);
      nc += __popcll(mk);
    }

    int idx;
    if (nc > 0) {
      // packed key: (bits23 << 9) | (511 - j); max -> max bits, tie -> min j
      uint32_t best = 0u;
      for (int c = lane; c < nc; c += 128) {
        int j1 = wcand[c];
        int c2 = c + 64;
        int j2 = (c2 < nc) ? wcand[c2] : j1;
        uint32_t ya0, ya1, yb0, yb1;
        threefry2x32_dual(kp0, kp1,
                          rowbase + (uint32_t)j1, rowbase + (uint32_t)j1 + HALFC,
                          rowbase + (uint32_t)j2, rowbase + (uint32_t)j2 + HALFC,
                          ya0, ya1, yb0, yb1);
        uint32_t y1v = take_hi ? ya1 : ya0;
        uint32_t key1 = (y1v & 0xFFFFFE00u) | (uint32_t)(511 - j1);
        if (key1 > best) best = key1;
        if (c2 < nc) {
          uint32_t y2v = take_hi ? yb1 : yb0;
          uint32_t key2 = (y2v & 0xFFFFFE00u) | (uint32_t)(511 - j2);
          if (key2 > best) best = key2;
        }
      }
      #pragma unroll
      for (int off = 32; off; off >>= 1) {
        uint32_t ob = (uint32_t)__shfl_xor((int)best, off);
        if (ob > best) best = ob;
      }
      idx = 511 - (int)(best & 0x1FFu);
    } else {
      idx = hard;
    }
    float neg_d = drow[idx];
    float tl = pos_d - neg_d + 1.0f;
    if (tl > 0.f) { wsum += (double)tl; wcnt++; }
  }

  if (lane == 0) { lsum[wave] = wsum; lcnt[wave] = wcnt; }
  __syncthreads();
  if (t == 0) {
    partials[bid] = lsum[0] + lsum[1] + lsum[2] + lsum[3];
    pcnt[bid] = (int)(lcnt[0] + lcnt[1] + lcnt[2] + lcnt[3]);
  }
}

// K3: deterministic fixed-order reduction of the 2048 block partials.
__global__ __launch_bounds__(256) void finalize_kernel(
    const double* __restrict__ partials, const int* __restrict__ pcnt,
    float* __restrict__ out) {
  __shared__ double ss[256];
  __shared__ int sc[256];
  int t = threadIdx.x;
  double s = 0.0;
  int c = 0;
  for (int k = t; k < NPART; k += 256) { s += partials[k]; c += pcnt[k]; }
  ss[t] = s; sc[t] = c;
  __syncthreads();
  for (int st = 128; st; st >>= 1) {
    if (t < st) { ss[t] += ss[t + st]; sc[t] += sc[t + st]; }
    __syncthreads();
  }
  if (t == 0) out[0] = sc[0] ? (float)(ss[0] / (double)sc[0]) : 0.0f;
}

extern "C" void kernel_launch(void* const* d_in, const int* in_sizes, int n_in,
                              void* d_out, int out_size, void* d_ws, size_t ws_size,
                              hipStream_t stream) {
  const float* emb = (const float*)d_in[0];
  const int* labels = (const int*)d_in[1];
  float* out = (float*)d_out;
  char* ws = (char*)d_ws;

  float* dist = (float*)ws;                            // 1 MB
  int* hard_idx = (int*)(ws + 1048576);                // 2 KB
  uint32_t* keys0 = (uint32_t*)(ws + 1048576 + 2048);  // 2 KB
  uint32_t* keys1 = (uint32_t*)(ws + 1048576 + 4096);  // 2 KB
  double* partials = (double*)(ws + 1048576 + 6144);   // 16 KB
  int* pcnt = (int*)(ws + 1048576 + 6144 + 16384);     // 8 KB

  dist_kernel<<<B, 512, 0, stream>>>(emb, labels, dist, hard_idx, keys0, keys1);
  triplet_kernel<<<B * SUB, 256, 0, stream>>>(dist, labels, hard_idx, keys0,
                                              keys1, partials, pcnt);
  finalize_kernel<<<1, 256, 0, stream>>>(partials, pcnt, out);
}